// Round 3
// baseline (120.270 us; speedup 1.0000x reference)
//
#include <hip/hip_runtime.h>
#include <math.h>

#define D      256
#define NSEC   10
#define EPS    1e-6f
#define SLICE  0.1f

// ws float layout
#define WS_SUMS 0                      // [0,2560) per-sector sums
#define WS_CNT  (NSEC * D)             // [2560,2570) per-sector counts
#define WS_DIST (NSEC * D + NSEC)      // [2570] distance accumulator
#define WS_DONE (NSEC * D + NSEC + 1)  // [2571] done-block counter (uint bits)
#define WS_ZERO_FLOATS (NSEC * D + NSEC + 2)

__global__ void k_zero(float* __restrict__ ws) {
    int i = blockIdx.x * blockDim.x + threadIdx.x;
    if (i < WS_ZERO_FLOATS) ws[i] = 0.f;
}

__global__ __launch_bounds__(256) void k_sums(const float* __restrict__ emb,
                                              const int* __restrict__ sec,
                                              float* __restrict__ ws, int nrows) {
    const int lane = threadIdx.x & 63;
    const int wid  = threadIdx.x >> 6;          // 0..3
    const int gw   = blockIdx.x * 4 + wid;      // global wave id
    const int nw   = gridDim.x * 4;

    float4 acc[NSEC];
    float  cnt[NSEC];
#pragma unroll
    for (int s = 0; s < NSEC; ++s) { acc[s] = make_float4(0.f, 0.f, 0.f, 0.f); cnt[s] = 0.f; }

    const float* ep = emb + (size_t)lane * 4;

    auto accum = [&](int sv, float4 v) {
        const int s = __builtin_amdgcn_readfirstlane(sv);  // wave-uniform -> SGPR branch
#pragma unroll
        for (int ss = 0; ss < NSEC; ++ss) {
            if (s == ss) {   // scalar branch; acc index compile-time constant (no scratch)
                acc[ss].x += v.x; acc[ss].y += v.y; acc[ss].z += v.z; acc[ss].w += v.w;
                cnt[ss] += 1.f;
            }
        }
    };

    int r = gw;
    // unroll-8: 8 KB in flight per wave to hide HBM latency
    for (; r + 7 * nw < nrows; r += 8 * nw) {
        int   s0 = sec[r],          s1 = sec[r + nw],     s2 = sec[r + 2 * nw], s3 = sec[r + 3 * nw];
        int   s4 = sec[r + 4 * nw], s5 = sec[r + 5 * nw], s6 = sec[r + 6 * nw], s7 = sec[r + 7 * nw];
        float4 v0 = *reinterpret_cast<const float4*>(ep + (size_t)r * D);
        float4 v1 = *reinterpret_cast<const float4*>(ep + (size_t)(r + nw) * D);
        float4 v2 = *reinterpret_cast<const float4*>(ep + (size_t)(r + 2 * nw) * D);
        float4 v3 = *reinterpret_cast<const float4*>(ep + (size_t)(r + 3 * nw) * D);
        float4 v4 = *reinterpret_cast<const float4*>(ep + (size_t)(r + 4 * nw) * D);
        float4 v5 = *reinterpret_cast<const float4*>(ep + (size_t)(r + 5 * nw) * D);
        float4 v6 = *reinterpret_cast<const float4*>(ep + (size_t)(r + 6 * nw) * D);
        float4 v7 = *reinterpret_cast<const float4*>(ep + (size_t)(r + 7 * nw) * D);
        accum(s0, v0); accum(s1, v1); accum(s2, v2); accum(s3, v3);
        accum(s4, v4); accum(s5, v5); accum(s6, v6); accum(s7, v7);
    }
    for (; r < nrows; r += nw)
        accum(sec[r], *reinterpret_cast<const float4*>(ep + (size_t)r * D));

    // epilogue: per-wave private LDS slab (conflict-free b128 writes), one sync,
    // then all 256 threads tree-reduce (stride-1 b32 reads = free)
    __shared__ float lsum[4][NSEC * D];   // 40 KB
    __shared__ float lcnt[4][NSEC];
#pragma unroll
    for (int ss = 0; ss < NSEC; ++ss)
        *reinterpret_cast<float4*>(&lsum[wid][ss * D + lane * 4]) = acc[ss];
    if (lane == 0) {
#pragma unroll
        for (int ss = 0; ss < NSEC; ++ss) lcnt[wid][ss] = cnt[ss];
    }
    __syncthreads();

    const int t = threadIdx.x;
#pragma unroll
    for (int ss = 0; ss < NSEC; ++ss) {
        const int i = ss * D + t;
        atomicAdd(&ws[WS_SUMS + i], lsum[0][i] + lsum[1][i] + lsum[2][i] + lsum[3][i]);
    }
    if (t < NSEC)
        atomicAdd(&ws[WS_CNT + t], lcnt[0][t] + lcnt[1][t] + lcnt[2][t] + lcnt[3][t]);
}

// Fused: centers (per-block, from global sums) + distances + mean (last block writes out)
__global__ __launch_bounds__(256) void k_dist(const float* __restrict__ temb,
                                              const float* __restrict__ tsl,
                                              float* __restrict__ ws,
                                              float* __restrict__ out,
                                              int nrows, float invN) {
    __shared__ float lc[NSEC * D];
    for (int i = threadIdx.x; i < NSEC * D; i += 256) {
        const int s = i >> 8;  // i / D
        lc[i] = ws[WS_SUMS + i] / ws[WS_CNT + s];
    }
    __syncthreads();

    const int lane = threadIdx.x & 63;
    const int wid  = threadIdx.x >> 6;
    const int gw   = blockIdx.x * 4 + wid;
    const int nw   = gridDim.x * 4;

    const float* tp = temb + (size_t)lane * 4;

    auto rowdist = [&](float si, float4 v) -> float {
        int s = (int)floorf(si / SLICE);   // exact reference semantics: divide, floor, clip
        s = s < 0 ? 0 : (s > NSEC - 1 ? NSEC - 1 : s);
        const float4 c = *reinterpret_cast<const float4*>(&lc[s * D + lane * 4]);
        const float dx = v.x - c.x + EPS;
        const float dy = v.y - c.y + EPS;
        const float dz = v.z - c.z + EPS;
        const float dw = v.w - c.w + EPS;
        float loc = dx * dx + dy * dy + dz * dz + dw * dw;
#pragma unroll
        for (int off = 32; off >= 1; off >>= 1) loc += __shfl_xor(loc, off, 64);
        return loc;   // full row sum-of-squares, replicated across lanes
    };

    float wacc = 0.f;
    int r = gw;
    for (; r + 7 * nw < nrows; r += 8 * nw) {
        float t0 = tsl[r],          t1 = tsl[r + nw],     t2 = tsl[r + 2 * nw], t3 = tsl[r + 3 * nw];
        float t4 = tsl[r + 4 * nw], t5 = tsl[r + 5 * nw], t6 = tsl[r + 6 * nw], t7 = tsl[r + 7 * nw];
        float4 v0 = *reinterpret_cast<const float4*>(tp + (size_t)r * D);
        float4 v1 = *reinterpret_cast<const float4*>(tp + (size_t)(r + nw) * D);
        float4 v2 = *reinterpret_cast<const float4*>(tp + (size_t)(r + 2 * nw) * D);
        float4 v3 = *reinterpret_cast<const float4*>(tp + (size_t)(r + 3 * nw) * D);
        float4 v4 = *reinterpret_cast<const float4*>(tp + (size_t)(r + 4 * nw) * D);
        float4 v5 = *reinterpret_cast<const float4*>(tp + (size_t)(r + 5 * nw) * D);
        float4 v6 = *reinterpret_cast<const float4*>(tp + (size_t)(r + 6 * nw) * D);
        float4 v7 = *reinterpret_cast<const float4*>(tp + (size_t)(r + 7 * nw) * D);
        float l0 = rowdist(t0, v0), l1 = rowdist(t1, v1);
        float l2 = rowdist(t2, v2), l3 = rowdist(t3, v3);
        float l4 = rowdist(t4, v4), l5 = rowdist(t5, v5);
        float l6 = rowdist(t6, v6), l7 = rowdist(t7, v7);
        if (lane == 0)
            wacc += sqrtf(l0) + sqrtf(l1) + sqrtf(l2) + sqrtf(l3)
                  + sqrtf(l4) + sqrtf(l5) + sqrtf(l6) + sqrtf(l7);
    }
    for (; r < nrows; r += nw) {
        float l = rowdist(tsl[r], *reinterpret_cast<const float4*>(tp + (size_t)r * D));
        if (lane == 0) wacc += sqrtf(l);
    }

    __shared__ float wsum[4];
    if (lane == 0) wsum[wid] = wacc;
    __syncthreads();
    if (threadIdx.x == 0) {
        atomicAdd(&ws[WS_DIST], wsum[0] + wsum[1] + wsum[2] + wsum[3]);
        __threadfence();   // make the add visible device-wide before signaling done
        unsigned prev = atomicAdd(reinterpret_cast<unsigned*>(&ws[WS_DONE]), 1u);
        if (prev == gridDim.x - 1) {
            const float tot = atomicAdd(&ws[WS_DIST], 0.0f);  // device-scope coherent read
            out[0] = tot * invN;
        }
    }
}

extern "C" void kernel_launch(void* const* d_in, const int* in_sizes, int n_in,
                              void* d_out, int out_size, void* d_ws, size_t ws_size,
                              hipStream_t stream) {
    const float* semb = (const float*)d_in[0];   // [nS, 256] f32
    const int*   ssec = (const int*)d_in[1];     // [nS] i32
    const float* temb = (const float*)d_in[2];   // [nT, 256] f32
    const float* tsl  = (const float*)d_in[3];   // [nT] f32
    float* ws  = (float*)d_ws;
    float* out = (float*)d_out;
    const int nS = in_sizes[1];
    const int nT = in_sizes[3];

    hipLaunchKernelGGL(k_zero, dim3((WS_ZERO_FLOATS + 255) / 256), dim3(256), 0, stream, ws);
    hipLaunchKernelGGL(k_sums, dim3(1024), dim3(256), 0, stream, semb, ssec, ws, nS);
    hipLaunchKernelGGL(k_dist, dim3(1024), dim3(256), 0, stream, temb, tsl, ws, out,
                       nT, 1.0f / (float)nT);
}